// Round 1
// baseline (360.962 us; speedup 1.0000x reference)
//
#include <hip/hip_runtime.h>

// ---------------------------------------------------------------------------
// SelfAttention: B=4, S=2048, D=1024, fp32 in/out, causal, no 1/sqrt(d).
// Strategy: fp16 MFMA (16x16x32) for all GEMMs, fp32 accumulate, fp32 softmax.
// ws layout (bytes):
//   [0,            16M)  Q  fp16 (8192x1024)      } after softmax this region
//   [16M,          32M)  K  fp16 (8192x1024)      } is reused for P fp16
//   [32M,          48M)  V  fp16 (8192x1024)
//   [48M,         112M)  S  fp32 (4x2048x2048)    } after softmax reused for Vt
// total 117,440,512 bytes
// ---------------------------------------------------------------------------

typedef _Float16 h8 __attribute__((ext_vector_type(8)));
typedef float f32x4 __attribute__((ext_vector_type(4)));

#define BM 128
#define BN 128
#define BK 32
#define LPAD 40   // 32 halves + 8 pad (16B) -> row stride 80B, keeps b128 align

// NT GEMM: C[m][n] = sum_k A[m][k]*B[n][k]. A: MxK row-major, B: NxK row-major.
// IN_F32: A,B are fp32, converted to fp16 during LDS staging.
// OUT_F16: C stored fp16, else fp32.
// CAUSAL_SKIP: skip tiles with blockIdx.x > blockIdx.y (fully masked score tiles).
// K_LIMIT: clip K loop at m0+BM (PV: P[m][k]==0 for k>m).
template<bool IN_F32, bool OUT_F16, bool CAUSAL_SKIP, bool K_LIMIT>
__global__ __launch_bounds__(256) void gemm_nt(
    const void* __restrict__ Ap_, const void* __restrict__ Bp_,
    void* __restrict__ Cp_,
    int N, int K, size_t sAz, size_t sBz, size_t sCz)
{
    if (CAUSAL_SKIP && blockIdx.x > blockIdx.y) return;

    __shared__ _Float16 As[BM][LPAD];
    __shared__ _Float16 Bs[BN][LPAD];

    const int tid = threadIdx.x;
    const int m0 = blockIdx.y * BM;
    const int n0 = blockIdx.x * BN;
    const size_t z = blockIdx.z;

    // staging: thread t handles row t/2 (0..127), 16 halves at k offset (t&1)*16
    const int sr = tid >> 1;
    const int sg = (tid & 1) * 16;
    const size_t ArowOff = (size_t)(m0 + sr) * K;
    const size_t BrowOff = (size_t)(n0 + sr) * K;

    // MFMA geometry: 4 waves in 2x2, each wave 64x64 = 4x4 frags of 16x16
    const int lane = tid & 63;
    const int wv = tid >> 6;
    const int wm = (wv >> 1) * 64;
    const int wn = (wv & 1) * 64;
    const int la = lane & 15;   // A: m-row / B: n-col / D: col
    const int qd = lane >> 4;   // k-block (input) / row-quad (output)

    f32x4 acc[4][4];
    #pragma unroll
    for (int i = 0; i < 4; i++)
        #pragma unroll
        for (int j = 0; j < 4; j++)
            acc[i][j] = (f32x4){0.f, 0.f, 0.f, 0.f};

    int kEnd = K;
    if (K_LIMIT) kEnd = (m0 + BM < K) ? (m0 + BM) : K;

    for (int k0 = 0; k0 < kEnd; k0 += BK) {
        if (IN_F32) {
            const float* A = (const float*)Ap_ + z * sAz + ArowOff + k0 + sg;
            const float* B = (const float*)Bp_ + z * sBz + BrowOff + k0 + sg;
            float4 a0 = *(const float4*)(A);
            float4 a1 = *(const float4*)(A + 4);
            float4 a2 = *(const float4*)(A + 8);
            float4 a3 = *(const float4*)(A + 12);
            float4 b0 = *(const float4*)(B);
            float4 b1 = *(const float4*)(B + 4);
            float4 b2 = *(const float4*)(B + 8);
            float4 b3 = *(const float4*)(B + 12);
            h8 ha0 = { (_Float16)a0.x, (_Float16)a0.y, (_Float16)a0.z, (_Float16)a0.w,
                       (_Float16)a1.x, (_Float16)a1.y, (_Float16)a1.z, (_Float16)a1.w };
            h8 ha1 = { (_Float16)a2.x, (_Float16)a2.y, (_Float16)a2.z, (_Float16)a2.w,
                       (_Float16)a3.x, (_Float16)a3.y, (_Float16)a3.z, (_Float16)a3.w };
            h8 hb0 = { (_Float16)b0.x, (_Float16)b0.y, (_Float16)b0.z, (_Float16)b0.w,
                       (_Float16)b1.x, (_Float16)b1.y, (_Float16)b1.z, (_Float16)b1.w };
            h8 hb1 = { (_Float16)b2.x, (_Float16)b2.y, (_Float16)b2.z, (_Float16)b2.w,
                       (_Float16)b3.x, (_Float16)b3.y, (_Float16)b3.z, (_Float16)b3.w };
            *(h8*)&As[sr][sg]     = ha0;
            *(h8*)&As[sr][sg + 8] = ha1;
            *(h8*)&Bs[sr][sg]     = hb0;
            *(h8*)&Bs[sr][sg + 8] = hb1;
        } else {
            const _Float16* A = (const _Float16*)Ap_ + z * sAz + ArowOff + k0 + sg;
            const _Float16* B = (const _Float16*)Bp_ + z * sBz + BrowOff + k0 + sg;
            *(uint4*)&As[sr][sg]     = *(const uint4*)A;
            *(uint4*)&As[sr][sg + 8] = *(const uint4*)(A + 8);
            *(uint4*)&Bs[sr][sg]     = *(const uint4*)B;
            *(uint4*)&Bs[sr][sg + 8] = *(const uint4*)(B + 8);
        }
        __syncthreads();

        h8 af[4], bf[4];
        #pragma unroll
        for (int i = 0; i < 4; i++) af[i] = *(const h8*)&As[wm + i * 16 + la][qd * 8];
        #pragma unroll
        for (int i = 0; i < 4; i++) bf[i] = *(const h8*)&Bs[wn + i * 16 + la][qd * 8];
        #pragma unroll
        for (int i = 0; i < 4; i++)
            #pragma unroll
            for (int j = 0; j < 4; j++)
                acc[i][j] = __builtin_amdgcn_mfma_f32_16x16x32_f16(af[i], bf[j], acc[i][j], 0, 0, 0);
        __syncthreads();
    }

    // epilogue: D layout col=lane&15, row=qd*4+reg
    if (OUT_F16) {
        _Float16* C = (_Float16*)Cp_ + z * sCz;
        #pragma unroll
        for (int i = 0; i < 4; i++)
            #pragma unroll
            for (int j = 0; j < 4; j++)
                #pragma unroll
                for (int rr = 0; rr < 4; rr++)
                    C[(size_t)(m0 + wm + i * 16 + qd * 4 + rr) * N + (n0 + wn + j * 16 + la)] =
                        (_Float16)acc[i][j][rr];
    } else {
        float* C = (float*)Cp_ + z * sCz;
        #pragma unroll
        for (int i = 0; i < 4; i++)
            #pragma unroll
            for (int j = 0; j < 4; j++)
                #pragma unroll
                for (int rr = 0; rr < 4; rr++)
                    C[(size_t)(m0 + wm + i * 16 + qd * 4 + rr) * N + (n0 + wn + j * 16 + la)] =
                        acc[i][j][rr];
    }
}

// causal row softmax: S fp32 (4x2048x2048) -> P fp16, zeros above diagonal.
__global__ __launch_bounds__(256) void softmax_causal(const float* __restrict__ S,
                                                      _Float16* __restrict__ P)
{
    const int idx = blockIdx.x;          // 0..8191
    const int q = idx & 2047;
    const float* Srow = S + (size_t)idx * 2048;
    _Float16* Prow = P + (size_t)idx * 2048;
    const int t = threadIdx.x;
    const int lane = t & 63, wv = t >> 6;
    __shared__ float red[4];

    float vals[8];
    float mx = -3.4e38f;
    #pragma unroll
    for (int i = 0; i < 8; i++) {
        int k = t + i * 256;
        float v = (k <= q) ? Srow[k] : -3.4e38f;
        vals[i] = v;
        mx = fmaxf(mx, v);
    }
    #pragma unroll
    for (int o = 32; o > 0; o >>= 1) mx = fmaxf(mx, __shfl_down(mx, o, 64));
    if (lane == 0) red[wv] = mx;
    __syncthreads();
    const float mall = fmaxf(fmaxf(red[0], red[1]), fmaxf(red[2], red[3]));
    __syncthreads();

    float sum = 0.f;
    #pragma unroll
    for (int i = 0; i < 8; i++) {
        int k = t + i * 256;
        float e = (k <= q) ? __expf(vals[i] - mall) : 0.f;
        vals[i] = e;
        sum += e;
    }
    #pragma unroll
    for (int o = 32; o > 0; o >>= 1) sum += __shfl_down(sum, o, 64);
    if (lane == 0) red[wv] = sum;
    __syncthreads();
    const float inv = 1.f / (red[0] + red[1] + red[2] + red[3]);

    #pragma unroll
    for (int i = 0; i < 8; i++)
        Prow[t + i * 256] = (_Float16)(vals[i] * inv);
}

// V (b,s,e) fp16 -> Vt (b,e,s) fp16, 64x64 LDS tiles
__global__ __launch_bounds__(256) void transpose_v_kernel(const _Float16* __restrict__ V,
                                                          _Float16* __restrict__ Vt)
{
    __shared__ _Float16 tile[64][72];
    const int b = blockIdx.z;
    const int s0 = blockIdx.x * 64;
    const int e0 = blockIdx.y * 64;
    const _Float16* Vb = V + (size_t)b * 2048 * 1024;
    _Float16* Vtb = Vt + (size_t)b * 1024 * 2048;
    const int r = threadIdx.x >> 2;          // 0..63
    const int c = (threadIdx.x & 3) * 16;    // 0,16,32,48

    const _Float16* src = &Vb[(size_t)(s0 + r) * 1024 + e0 + c];
    *(uint4*)&tile[r][c]     = *(const uint4*)src;
    *(uint4*)&tile[r][c + 8] = *(const uint4*)(src + 8);
    __syncthreads();

    h8 o0, o1;
    #pragma unroll
    for (int j = 0; j < 8; j++) o0[j] = tile[c + j][r];
    #pragma unroll
    for (int j = 0; j < 8; j++) o1[j] = tile[c + 8 + j][r];
    _Float16* dst = &Vtb[(size_t)(e0 + r) * 2048 + s0 + c];
    *(h8*)dst       = o0;
    *(h8*)(dst + 8) = o1;
}

extern "C" void kernel_launch(void* const* d_in, const int* in_sizes, int n_in,
                              void* d_out, int out_size, void* d_ws, size_t ws_size,
                              hipStream_t stream) {
    const float* x  = (const float*)d_in[0];
    const float* Wq = (const float*)d_in[1];
    const float* Wk = (const float*)d_in[2];
    const float* Wv = (const float*)d_in[3];
    float* out = (float*)d_out;

    char* ws = (char*)d_ws;
    _Float16* Qh = (_Float16*)(ws + 0);
    _Float16* Kh = (_Float16*)(ws + (size_t)16 * 1024 * 1024);
    _Float16* Vh = (_Float16*)(ws + (size_t)32 * 1024 * 1024);
    float*    S  = (float*)   (ws + (size_t)48 * 1024 * 1024);
    _Float16* P  = (_Float16*)(ws + 0);                          // over Q,K (dead)
    _Float16* Vt = (_Float16*)(ws + (size_t)48 * 1024 * 1024);   // over S  (dead)

    const dim3 blk(256);

    // 1) Q/K/V projections: 8192x1024 = x(8192x1024) @ W^T(1024x1024), fp16 out
    {
        dim3 g(1024 / BN, 8192 / BM, 1);
        gemm_nt<true, true, false, false><<<g, blk, 0, stream>>>(x, Wq, Qh, 1024, 1024, 0, 0, 0);
        gemm_nt<true, true, false, false><<<g, blk, 0, stream>>>(x, Wk, Kh, 1024, 1024, 0, 0, 0);
        gemm_nt<true, true, false, false><<<g, blk, 0, stream>>>(x, Wv, Vh, 1024, 1024, 0, 0, 0);
    }

    // 2) scores: S[b] = Q[b] @ K[b]^T (2048x2048), causal tiles skipped
    {
        dim3 g(2048 / BN, 2048 / BM, 4);
        gemm_nt<false, false, true, false><<<g, blk, 0, stream>>>(
            Qh, Kh, S, 2048, 1024,
            (size_t)2048 * 1024, (size_t)2048 * 1024, (size_t)2048 * 2048);
    }

    // 3) causal softmax rows -> P fp16
    softmax_causal<<<dim3(4 * 2048), blk, 0, stream>>>(S, P);

    // 4) V -> Vt (b,e,s)
    transpose_v_kernel<<<dim3(2048 / 64, 1024 / 64, 4), blk, 0, stream>>>(Vh, Vt);

    // 5) out[b] = P[b] (2048x2048) @ Vt[b]^T -> (2048x1024) fp32, K clipped causally
    {
        dim3 g(1024 / BN, 2048 / BM, 4);
        gemm_nt<false, false, false, true><<<g, blk, 0, stream>>>(
            P, Vt, out, 1024, 2048,
            (size_t)2048 * 2048, (size_t)1024 * 2048, (size_t)2048 * 1024);
    }
}

// Round 2
// 290.135 us; speedup vs baseline: 1.2441x; 1.2441x over previous
//
#include <hip/hip_runtime.h>

// ---------------------------------------------------------------------------
// SelfAttention: B=4, S=2048, D=1024, fp32 in/out, causal, no 1/sqrt(d).
// fp16 MFMA (16x16x32) everywhere, fp32 accumulate, fp32 softmax.
// GEMMs use global_load_lds width=16 staging (m97 structure, unpadded LDS).
//
// ws layout (MiB):
//   [0,48)    QKV fp16 (Q 0-16, K 16-32, V 32-48)
//   [48,112)  S fp32 (4x2048x2048)
//   [48,64)   x_h fp16      (over S; dead before S written)
//   [64,70)   Wh  fp16 x3   (over S; dead before S written)
//   [0,32)    P fp16        (over Q,K; written after scores read them)
//   [48,64)   Vt fp16       (over S; written after softmax reads S)
// total 112 MiB (same footprint as round 1, which fit).
// ---------------------------------------------------------------------------

typedef _Float16 h8 __attribute__((ext_vector_type(8)));
typedef float f32x4 __attribute__((ext_vector_type(4)));

#define BM 128
#define BN 128
#define BK 32

__device__ __forceinline__ void gl_lds16(const _Float16* g, _Float16* l) {
    __builtin_amdgcn_global_load_lds(
        (const __attribute__((address_space(1))) void*)g,
        (__attribute__((address_space(3))) void*)l, 16, 0, 0);
}

// NT GEMM: C[m][n] = sum_k A[m][k]*B[n][k]; A,B fp16 row-major K-contiguous.
// OUT_F16: store fp16 else fp32. TRI: gridDim.x is linear lower-triangle tile
// id (scores). KLIM: clip K at m0+BM (PV causal zeros).
template<bool OUT_F16, bool TRI, bool KLIM>
__global__ __launch_bounds__(256) void gemm_nt(
    const _Float16* __restrict__ A, const _Float16* __restrict__ B,
    void* __restrict__ Cp, int N, int K,
    size_t sAz, size_t sBz, size_t sCz)
{
    __shared__ _Float16 As[BM * BK];   // 8 KiB, unpadded (global_load_lds layout)
    __shared__ _Float16 Bs[BN * BK];

    int bx, by;
    if (TRI) {
        const int t = blockIdx.x;
        int i = (int)((sqrtf((float)(8 * t + 1)) - 1.0f) * 0.5f);
        while ((i + 1) * (i + 2) / 2 <= t) i++;
        while (i * (i + 1) / 2 > t) i--;
        by = i;
        bx = t - i * (i + 1) / 2;
    } else {
        bx = blockIdx.x;
        by = blockIdx.y;
    }

    const int tid  = threadIdx.x;
    const int lane = tid & 63;
    const int wv   = tid >> 6;
    const int m0 = by * BM, n0 = bx * BN;
    const size_t z = blockIdx.z;

    // staging: wave wv stages 1KiB chunks {wv, wv+4} of each tile.
    // chunk c = rows 16c..16c+15; lane l -> row 16c+(l>>2), col halves (l&3)*8;
    // LDS dst byte = c*1024 + l*16 (contiguous in lane order — required).
    const int lr = lane >> 2;
    const int lc = (lane & 3) * 8;
    const _Float16* pA0 = A + z * sAz + (size_t)(m0 + wv * 16 + lr) * K + lc;
    const _Float16* pA1 = pA0 + (size_t)64 * K;
    const _Float16* pB0 = B + z * sBz + (size_t)(n0 + wv * 16 + lr) * K + lc;
    const _Float16* pB1 = pB0 + (size_t)64 * K;
    _Float16* lA0 = As + wv * 512;
    _Float16* lA1 = As + (wv + 4) * 512;
    _Float16* lB0 = Bs + wv * 512;
    _Float16* lB1 = Bs + (wv + 4) * 512;

    // MFMA geometry: 4 waves 2x2, each wave 64x64 = 4x4 frags of 16x16x32
    const int la = lane & 15;
    const int qd = lane >> 4;
    const int wm = (wv >> 1) * 64;
    const int wn = (wv & 1) * 64;

    f32x4 acc[4][4];
    #pragma unroll
    for (int i = 0; i < 4; i++)
        #pragma unroll
        for (int j = 0; j < 4; j++)
            acc[i][j] = (f32x4){0.f, 0.f, 0.f, 0.f};

    const int kEnd = KLIM ? (m0 + BM) : K;

    for (int k0 = 0; k0 < kEnd; k0 += BK) {
        gl_lds16(pA0, lA0);
        gl_lds16(pA1, lA1);
        gl_lds16(pB0, lB0);
        gl_lds16(pB1, lB1);
        pA0 += BK; pA1 += BK; pB0 += BK; pB1 += BK;
        __syncthreads();   // compiler emits vmcnt(0) drain before s_barrier

        h8 af[4], bf[4];
        #pragma unroll
        for (int i = 0; i < 4; i++)
            af[i] = *(const h8*)&As[(wm + i * 16 + la) * BK + qd * 8];
        #pragma unroll
        for (int i = 0; i < 4; i++)
            bf[i] = *(const h8*)&Bs[(wn + i * 16 + la) * BK + qd * 8];
        #pragma unroll
        for (int i = 0; i < 4; i++)
            #pragma unroll
            for (int j = 0; j < 4; j++)
                acc[i][j] = __builtin_amdgcn_mfma_f32_16x16x32_f16(af[i], bf[j], acc[i][j], 0, 0, 0);
        __syncthreads();
    }

    // epilogue: D layout col=lane&15, row=qd*4+reg
    if (OUT_F16) {
        _Float16* C = (_Float16*)Cp + z * sCz;
        #pragma unroll
        for (int i = 0; i < 4; i++)
            #pragma unroll
            for (int j = 0; j < 4; j++)
                #pragma unroll
                for (int rr = 0; rr < 4; rr++)
                    C[(size_t)(m0 + wm + i * 16 + qd * 4 + rr) * N + (n0 + wn + j * 16 + la)] =
                        (_Float16)acc[i][j][rr];
    } else {
        float* C = (float*)Cp + z * sCz;
        #pragma unroll
        for (int i = 0; i < 4; i++)
            #pragma unroll
            for (int j = 0; j < 4; j++)
                #pragma unroll
                for (int rr = 0; rr < 4; rr++)
                    C[(size_t)(m0 + wm + i * 16 + qd * 4 + rr) * N + (n0 + wn + j * 16 + la)] =
                        acc[i][j][rr];
    }
}

// fp32 -> fp16, 8 elems/thread
__global__ __launch_bounds__(256) void cvt8(const float* __restrict__ in,
                                            _Float16* __restrict__ out)
{
    const size_t i = ((size_t)blockIdx.x * 256 + threadIdx.x) * 8;
    float4 a = *(const float4*)(in + i);
    float4 b = *(const float4*)(in + i + 4);
    h8 o = { (_Float16)a.x, (_Float16)a.y, (_Float16)a.z, (_Float16)a.w,
             (_Float16)b.x, (_Float16)b.y, (_Float16)b.z, (_Float16)b.w };
    *(h8*)(out + i) = o;
}

__global__ __launch_bounds__(256) void cvt_w3(const float* __restrict__ Wq,
                                              const float* __restrict__ Wk,
                                              const float* __restrict__ Wv,
                                              _Float16* __restrict__ out)
{
    const int zz = blockIdx.y;
    const float* in = (zz == 0) ? Wq : ((zz == 1) ? Wk : Wv);
    const size_t i = ((size_t)blockIdx.x * 256 + threadIdx.x) * 8;
    float4 a = *(const float4*)(in + i);
    float4 b = *(const float4*)(in + i + 4);
    h8 o = { (_Float16)a.x, (_Float16)a.y, (_Float16)a.z, (_Float16)a.w,
             (_Float16)b.x, (_Float16)b.y, (_Float16)b.z, (_Float16)b.w };
    *(h8*)(out + (size_t)zz * 1048576 + i) = o;
}

// causal row softmax: S fp32 (4x2048x2048) -> P fp16, zeros above diagonal.
__global__ __launch_bounds__(256) void softmax_causal(const float* __restrict__ S,
                                                      _Float16* __restrict__ P)
{
    const int idx = blockIdx.x;          // 0..8191
    const int q = idx & 2047;
    const float* Srow = S + (size_t)idx * 2048;
    _Float16* Prow = P + (size_t)idx * 2048;
    const int t = threadIdx.x;
    const int lane = t & 63, wv = t >> 6;
    __shared__ float red[4];

    float vals[8];
    float mx = -3.4e38f;
    #pragma unroll
    for (int i = 0; i < 8; i++) {
        int k = t + i * 256;
        float v = (k <= q) ? Srow[k] : -3.4e38f;
        vals[i] = v;
        mx = fmaxf(mx, v);
    }
    #pragma unroll
    for (int o = 32; o > 0; o >>= 1) mx = fmaxf(mx, __shfl_down(mx, o, 64));
    if (lane == 0) red[wv] = mx;
    __syncthreads();
    const float mall = fmaxf(fmaxf(red[0], red[1]), fmaxf(red[2], red[3]));
    __syncthreads();

    float sum = 0.f;
    #pragma unroll
    for (int i = 0; i < 8; i++) {
        int k = t + i * 256;
        float e = (k <= q) ? __expf(vals[i] - mall) : 0.f;
        vals[i] = e;
        sum += e;
    }
    #pragma unroll
    for (int o = 32; o > 0; o >>= 1) sum += __shfl_down(sum, o, 64);
    if (lane == 0) red[wv] = sum;
    __syncthreads();
    const float inv = 1.f / (red[0] + red[1] + red[2] + red[3]);

    #pragma unroll
    for (int i = 0; i < 8; i++)
        Prow[t + i * 256] = (_Float16)(vals[i] * inv);
}

// V (b,s,e) fp16 -> Vt (b,e,s) fp16, 64x64 LDS tiles
__global__ __launch_bounds__(256) void transpose_v_kernel(const _Float16* __restrict__ V,
                                                          _Float16* __restrict__ Vt)
{
    __shared__ _Float16 tile[64][72];
    const int b = blockIdx.z;
    const int s0 = blockIdx.x * 64;
    const int e0 = blockIdx.y * 64;
    const _Float16* Vb = V + (size_t)b * 2048 * 1024;
    _Float16* Vtb = Vt + (size_t)b * 1024 * 2048;
    const int r = threadIdx.x >> 2;
    const int c = (threadIdx.x & 3) * 16;

    const _Float16* src = &Vb[(size_t)(s0 + r) * 1024 + e0 + c];
    *(uint4*)&tile[r][c]     = *(const uint4*)src;
    *(uint4*)&tile[r][c + 8] = *(const uint4*)(src + 8);
    __syncthreads();

    h8 o0, o1;
    #pragma unroll
    for (int j = 0; j < 8; j++) o0[j] = tile[c + j][r];
    #pragma unroll
    for (int j = 0; j < 8; j++) o1[j] = tile[c + 8 + j][r];
    _Float16* dst = &Vtb[(size_t)(e0 + r) * 2048 + s0 + c];
    *(h8*)dst       = o0;
    *(h8*)(dst + 8) = o1;
}

extern "C" void kernel_launch(void* const* d_in, const int* in_sizes, int n_in,
                              void* d_out, int out_size, void* d_ws, size_t ws_size,
                              hipStream_t stream) {
    const float* x  = (const float*)d_in[0];
    const float* Wq = (const float*)d_in[1];
    const float* Wk = (const float*)d_in[2];
    const float* Wv = (const float*)d_in[3];
    float* out = (float*)d_out;

    const size_t MiB = 1024 * 1024;
    char* ws = (char*)d_ws;
    _Float16* QKVh = (_Float16*)ws;                     // 48 MiB
    _Float16* Vh   = QKVh + (size_t)2 * 8388608;        // V at +32 MiB
    float*    S    = (float*)(ws + 48 * MiB);           // 64 MiB
    _Float16* x_h  = (_Float16*)(ws + 48 * MiB);        // 16 MiB (over S)
    _Float16* Wh   = (_Float16*)(ws + 64 * MiB);        // 6 MiB  (over S)
    _Float16* P    = (_Float16*)ws;                     // 32 MiB (over Q,K)
    _Float16* Vt   = (_Float16*)(ws + 48 * MiB);        // 16 MiB (over S)

    const dim3 blk(256);

    // 0) fp32 -> fp16 conversions
    cvt8<<<dim3(4096), blk, 0, stream>>>(x, x_h);                       // 8M elems
    cvt_w3<<<dim3(512, 3), blk, 0, stream>>>(Wq, Wk, Wv, Wh);           // 3x1M

    // 1) QKV: one dispatch, z selects weight (sBz) and output slab (sCz)
    gemm_nt<true, false, false><<<dim3(8, 64, 3), blk, 0, stream>>>(
        x_h, Wh, QKVh, 1024, 1024,
        (size_t)0, (size_t)1048576, (size_t)8388608);

    // 2) scores: lower-triangle tiles only (136/batch)
    gemm_nt<false, true, false><<<dim3(136, 1, 4), blk, 0, stream>>>(
        QKVh, QKVh + 8388608, S, 2048, 1024,
        (size_t)2097152, (size_t)2097152, (size_t)4194304);

    // 3) causal softmax rows -> P fp16 (over Q,K)
    softmax_causal<<<dim3(4 * 2048), blk, 0, stream>>>(S, P);

    // 4) V -> Vt (b,e,s) (over S)
    transpose_v_kernel<<<dim3(32, 16, 4), blk, 0, stream>>>(Vh, Vt);

    // 5) out = P @ Vt^T, fp32 out, K clipped at m0+128
    gemm_nt<false, false, true><<<dim3(8, 16, 4), blk, 0, stream>>>(
        P, Vt, out, 1024, 2048,
        (size_t)4194304, (size_t)2097152, (size_t)2097152);
}

// Round 3
// 283.255 us; speedup vs baseline: 1.2743x; 1.0243x over previous
//
#include <hip/hip_runtime.h>

// ---------------------------------------------------------------------------
// SelfAttention: B=4, S=2048, D=1024, fp32 in/out, causal, no 1/sqrt(d).
// fp16 MFMA (16x16x32), fp32 accumulate, fp32 softmax.
// R3: XCD-residue swizzles for L2 locality (id%8 -> XCD heuristic), fused
// single-dispatch QKV (N=3072, slab-store epilogue), balanced triangular
// decode for scores/PV, softmax read/write clipping.
//
// ws layout (MiB):
//   [0,48)    QKV fp16 slabs (Q 0-16, K 16-32, V 32-48)
//   [48,112)  S fp32 (4x2048x2048)
//   [48,64)   x_h fp16      (over S; dead before S written)
//   [64,70)   Wh  fp16 [3072,1024] (over S; dead before S written)
//   [0,32)    P fp16        (over Q,K; written after scores read them)
//   [48,64)   Vt fp16       (over S; written after softmax reads S)
// ---------------------------------------------------------------------------

typedef _Float16 h8 __attribute__((ext_vector_type(8)));
typedef float f32x4 __attribute__((ext_vector_type(4)));

#define BM 128
#define BN 128
#define BK 32

__device__ __forceinline__ void gl_lds16(const _Float16* g, _Float16* l) {
    __builtin_amdgcn_global_load_lds(
        (const __attribute__((address_space(1))) void*)g,
        (__attribute__((address_space(3))) void*)l, 16, 0, 0);
}

// NT GEMM: C[m][n] = sum_k A[m][k]*B[n][k]; A,B fp16 row-major, row stride K.
// SWZ: 1 = QKV residue (grid.x=1536, bx 0..23, by 0..63, XCD owns by%8)
//      2 = scores balanced triangle (grid.x=136, XCD r owns rows {r,15-r})
//      3 = PV residue (grid.x=128, by in {r,15-r}, pid_n 0..7)
// OM:  0 = fp32 C (ldc=N), 1 = fp16 C (ldc=N), 2 = fp16 slab store (QKV)
// KLIM: clip K loop at m0+BM (PV causal zeros).
template<int SWZ, int OM, bool KLIM>
__global__ __launch_bounds__(256) void gemm_nt(
    const _Float16* __restrict__ A, const _Float16* __restrict__ B,
    void* __restrict__ Cp, int N, int K,
    size_t sAz, size_t sBz, size_t sCz)
{
    __shared__ _Float16 As[BM * BK];   // 8 KiB, unpadded (global_load_lds layout)
    __shared__ _Float16 Bs[BN * BK];

    int bx, by;
    if (SWZ == 1) {
        const int r = blockIdx.x & 7, q2 = blockIdx.x >> 3;
        bx = q2 >> 3;
        by = ((q2 & 7) << 3) | r;
    } else if (SWZ == 2) {
        const int r = blockIdx.x & 7, g = blockIdx.x >> 3;   // g in 0..16
        if (g <= r) { by = r;      bx = g; }
        else        { by = 15 - r; bx = g - (r + 1); }
    } else if (SWZ == 3) {
        const int r = blockIdx.x & 7, g = blockIdx.x >> 3;   // g in 0..15
        by = (g & 1) ? (15 - r) : r;
        bx = g >> 1;
    } else {
        bx = blockIdx.x; by = blockIdx.y;
    }

    const int tid  = threadIdx.x;
    const int lane = tid & 63;
    const int wv   = tid >> 6;
    const int m0 = by * BM, n0 = bx * BN;
    const size_t z = blockIdx.z;

    // staging: wave wv stages 1KiB chunks {wv, wv+4}; lane l -> row 16c+(l>>2),
    // col halves (l&3)*8; LDS dst = c*1024B + l*16B (lane-contiguous, required).
    const int lr = lane >> 2;
    const int lc = (lane & 3) * 8;
    const _Float16* pA0 = A + z * sAz + (size_t)(m0 + wv * 16 + lr) * K + lc;
    const _Float16* pA1 = pA0 + (size_t)64 * K;
    const _Float16* pB0 = B + z * sBz + (size_t)(n0 + wv * 16 + lr) * K + lc;
    const _Float16* pB1 = pB0 + (size_t)64 * K;
    _Float16* lA0 = As + wv * 512;
    _Float16* lA1 = As + (wv + 4) * 512;
    _Float16* lB0 = Bs + wv * 512;
    _Float16* lB1 = Bs + (wv + 4) * 512;

    // MFMA geometry: 4 waves 2x2, each wave 64x64 = 4x4 frags of 16x16x32
    const int la = lane & 15;
    const int qd = lane >> 4;
    const int wm = (wv >> 1) * 64;
    const int wn = (wv & 1) * 64;

    f32x4 acc[4][4];
    #pragma unroll
    for (int i = 0; i < 4; i++)
        #pragma unroll
        for (int j = 0; j < 4; j++)
            acc[i][j] = (f32x4){0.f, 0.f, 0.f, 0.f};

    const int kEnd = KLIM ? (m0 + BM) : K;

    for (int k0 = 0; k0 < kEnd; k0 += BK) {
        gl_lds16(pA0, lA0);
        gl_lds16(pA1, lA1);
        gl_lds16(pB0, lB0);
        gl_lds16(pB1, lB1);
        pA0 += BK; pA1 += BK; pB0 += BK; pB1 += BK;
        __syncthreads();

        h8 af[4], bf[4];
        #pragma unroll
        for (int i = 0; i < 4; i++)
            af[i] = *(const h8*)&As[(wm + i * 16 + la) * BK + qd * 8];
        #pragma unroll
        for (int i = 0; i < 4; i++)
            bf[i] = *(const h8*)&Bs[(wn + i * 16 + la) * BK + qd * 8];
        #pragma unroll
        for (int i = 0; i < 4; i++)
            #pragma unroll
            for (int j = 0; j < 4; j++)
                acc[i][j] = __builtin_amdgcn_mfma_f32_16x16x32_f16(af[i], bf[j], acc[i][j], 0, 0, 0);
        __syncthreads();
    }

    // epilogue: D layout col=lane&15, row=qd*4+reg
    if (OM == 2) {
        // slab store: col 0..3071 -> slab col>>10, within-slab ld 1024
        _Float16* C = (_Float16*)Cp;
        #pragma unroll
        for (int i = 0; i < 4; i++)
            #pragma unroll
            for (int j = 0; j < 4; j++) {
                const int col  = n0 + wn + j * 16 + la;
                const size_t base = (size_t)(col >> 10) * 8388608 + (col & 1023);
                #pragma unroll
                for (int rr = 0; rr < 4; rr++)
                    C[base + (size_t)(m0 + wm + i * 16 + qd * 4 + rr) * 1024] =
                        (_Float16)acc[i][j][rr];
            }
    } else if (OM == 1) {
        _Float16* C = (_Float16*)Cp + z * sCz;
        #pragma unroll
        for (int i = 0; i < 4; i++)
            #pragma unroll
            for (int j = 0; j < 4; j++)
                #pragma unroll
                for (int rr = 0; rr < 4; rr++)
                    C[(size_t)(m0 + wm + i * 16 + qd * 4 + rr) * N + (n0 + wn + j * 16 + la)] =
                        (_Float16)acc[i][j][rr];
    } else {
        float* C = (float*)Cp + z * sCz;
        #pragma unroll
        for (int i = 0; i < 4; i++)
            #pragma unroll
            for (int j = 0; j < 4; j++)
                #pragma unroll
                for (int rr = 0; rr < 4; rr++)
                    C[(size_t)(m0 + wm + i * 16 + qd * 4 + rr) * N + (n0 + wn + j * 16 + la)] =
                        acc[i][j][rr];
    }
}

// fp32 -> fp16, 8 elems/thread
__global__ __launch_bounds__(256) void cvt8(const float* __restrict__ in,
                                            _Float16* __restrict__ out)
{
    const size_t i = ((size_t)blockIdx.x * 256 + threadIdx.x) * 8;
    float4 a = *(const float4*)(in + i);
    float4 b = *(const float4*)(in + i + 4);
    h8 o = { (_Float16)a.x, (_Float16)a.y, (_Float16)a.z, (_Float16)a.w,
             (_Float16)b.x, (_Float16)b.y, (_Float16)b.z, (_Float16)b.w };
    *(h8*)(out + i) = o;
}

__global__ __launch_bounds__(256) void cvt_w3(const float* __restrict__ Wq,
                                              const float* __restrict__ Wk,
                                              const float* __restrict__ Wv,
                                              _Float16* __restrict__ out)
{
    const int zz = blockIdx.y;
    const float* in = (zz == 0) ? Wq : ((zz == 1) ? Wk : Wv);
    const size_t i = ((size_t)blockIdx.x * 256 + threadIdx.x) * 8;
    float4 a = *(const float4*)(in + i);
    float4 b = *(const float4*)(in + i + 4);
    h8 o = { (_Float16)a.x, (_Float16)a.y, (_Float16)a.z, (_Float16)a.w,
             (_Float16)b.x, (_Float16)b.y, (_Float16)b.z, (_Float16)b.w };
    *(h8*)(out + (size_t)zz * 1048576 + i) = o;
}

// causal row softmax: S fp32 -> P fp16. Reads only k<=q chunks; writes only
// k < 128-ceil(q+1) (PV's KLIM never reads beyond).
__global__ __launch_bounds__(256) void softmax_causal(const float* __restrict__ S,
                                                      _Float16* __restrict__ P)
{
    const int idx = blockIdx.x;          // 0..8191
    const int q = idx & 2047;
    const float* Srow = S + (size_t)idx * 2048;
    _Float16* Prow = P + (size_t)idx * 2048;
    const int t = threadIdx.x;
    const int lane = t & 63, wv = t >> 6;
    __shared__ float red[4];

    float vals[8];
    float mx = -3.4e38f;
    #pragma unroll
    for (int i = 0; i < 8; i++) {
        vals[i] = -3.4e38f;
        if (i * 256 <= q) {                      // block-uniform branch
            int k = t + i * 256;
            if (k <= q) vals[i] = Srow[k];
            mx = fmaxf(mx, vals[i]);
        }
    }
    #pragma unroll
    for (int o = 32; o > 0; o >>= 1) mx = fmaxf(mx, __shfl_down(mx, o, 64));
    if (lane == 0) red[wv] = mx;
    __syncthreads();
    const float mall = fmaxf(fmaxf(red[0], red[1]), fmaxf(red[2], red[3]));
    __syncthreads();

    float sum = 0.f;
    #pragma unroll
    for (int i = 0; i < 8; i++) {
        if (i * 256 <= q) {
            int k = t + i * 256;
            float e = (k <= q) ? __expf(vals[i] - mall) : 0.f;
            vals[i] = e;
            sum += e;
        } else vals[i] = 0.f;
    }
    #pragma unroll
    for (int o = 32; o > 0; o >>= 1) sum += __shfl_down(sum, o, 64);
    if (lane == 0) red[wv] = sum;
    __syncthreads();
    const float inv = 1.f / (red[0] + red[1] + red[2] + red[3]);

    const int kceil = ((q >> 7) + 1) << 7;       // PV reads cols < kceil
    #pragma unroll
    for (int i = 0; i < 8; i++) {
        if (i * 256 >= kceil) break;             // uniform
        int k = t + i * 256;
        if (k < kceil) Prow[k] = (_Float16)(vals[i] * inv);
    }
}

// V (b,s,e) fp16 -> Vt (b,e,s) fp16, 64x64 LDS tiles
__global__ __launch_bounds__(256) void transpose_v_kernel(const _Float16* __restrict__ V,
                                                          _Float16* __restrict__ Vt)
{
    __shared__ _Float16 tile[64][72];
    const int b = blockIdx.z;
    const int s0 = blockIdx.x * 64;
    const int e0 = blockIdx.y * 64;
    const _Float16* Vb = V + (size_t)b * 2048 * 1024;
    _Float16* Vtb = Vt + (size_t)b * 1024 * 2048;
    const int r = threadIdx.x >> 2;
    const int c = (threadIdx.x & 3) * 16;

    const _Float16* src = &Vb[(size_t)(s0 + r) * 1024 + e0 + c];
    *(uint4*)&tile[r][c]     = *(const uint4*)src;
    *(uint4*)&tile[r][c + 8] = *(const uint4*)(src + 8);
    __syncthreads();

    h8 o0, o1;
    #pragma unroll
    for (int j = 0; j < 8; j++) o0[j] = tile[c + j][r];
    #pragma unroll
    for (int j = 0; j < 8; j++) o1[j] = tile[c + 8 + j][r];
    _Float16* dst = &Vtb[(size_t)(e0 + r) * 2048 + s0 + c];
    *(h8*)dst       = o0;
    *(h8*)(dst + 8) = o1;
}

extern "C" void kernel_launch(void* const* d_in, const int* in_sizes, int n_in,
                              void* d_out, int out_size, void* d_ws, size_t ws_size,
                              hipStream_t stream) {
    const float* x  = (const float*)d_in[0];
    const float* Wq = (const float*)d_in[1];
    const float* Wk = (const float*)d_in[2];
    const float* Wv = (const float*)d_in[3];
    float* out = (float*)d_out;

    const size_t MiB = 1024 * 1024;
    char* ws = (char*)d_ws;
    _Float16* QKVh = (_Float16*)ws;                     // 48 MiB (3 slabs)
    _Float16* Vh   = QKVh + (size_t)2 * 8388608;        // V slab at +32 MiB
    float*    S    = (float*)(ws + 48 * MiB);           // 64 MiB
    _Float16* x_h  = (_Float16*)(ws + 48 * MiB);        // 16 MiB (over S)
    _Float16* Wh   = (_Float16*)(ws + 64 * MiB);        // 6 MiB  (over S)
    _Float16* P    = (_Float16*)ws;                     // 32 MiB (over Q,K)
    _Float16* Vt   = (_Float16*)(ws + 48 * MiB);        // 16 MiB (over S)

    const dim3 blk(256);

    // 0) fp32 -> fp16 conversions (Wh = concatenated [3072,1024])
    cvt8<<<dim3(4096), blk, 0, stream>>>(x, x_h);
    cvt_w3<<<dim3(512, 3), blk, 0, stream>>>(Wq, Wk, Wv, Wh);

    // 1) QKV fused: M=8192, N=3072, XCD-residue swizzle, slab-store epilogue
    gemm_nt<1, 2, false><<<dim3(1536), blk, 0, stream>>>(
        x_h, Wh, QKVh, 3072, 1024, 0, 0, 0);

    // 2) scores: balanced lower-triangle decode, 136 tiles/batch, 0 idle
    gemm_nt<2, 0, false><<<dim3(136, 1, 4), blk, 0, stream>>>(
        QKVh, QKVh + 8388608, S, 2048, 1024,
        (size_t)2097152, (size_t)2097152, (size_t)4194304);

    // 3) causal softmax rows -> P fp16 (over Q,K)
    softmax_causal<<<dim3(4 * 2048), blk, 0, stream>>>(S, P);

    // 4) V -> Vt (b,e,s) (over S)
    transpose_v_kernel<<<dim3(32, 16, 4), blk, 0, stream>>>(Vh, Vt);

    // 5) out = P @ Vt^T, fp32 out, K clipped at m0+128, residue swizzle
    gemm_nt<3, 0, true><<<dim3(128, 1, 4), blk, 0, stream>>>(
        P, Vt, out, 1024, 2048,
        (size_t)4194304, (size_t)2097152, (size_t)2097152);
}